// Round 4
// baseline (229.636 us; speedup 1.0000x reference)
//
#include <hip/hip_runtime.h>
#include <math.h>

// DiceLoss: B=8, C=19, H=W=512. logits fp32 [B,C,H,W], targets int [B,H,W].
// Round 11: DENSE global sweep + LDS staging.
// Dead theories (all wave-local): L1 policy (R7 null), outstanding-count
// (R8 -3%), burst length (R9 confounded), duty cycle / double-buffer
// (R10 exact null: 229.375 vs R7 229.380).
// Live theory: GLOBAL address footprint. R7/R10 = ~4096 waves x 20 streams
// at 1-MiB stride = ~80K scattered 512-B access points -> DRAM row thrash
// (~256-512 B per row activate) -> ~2 TB/s wall (observed 1.87). A copy
// kernel presents ONE dense sweeping window -> 6.3 TB/s.
// Fix: 512 blocks (exactly 2/CU); at iteration it, block b owns tile
// (it*512+b) -> the 512 concurrent tiles are CONSECUTIVE 4-KiB chunks of
// each channel plane: 19+1 dense 2-MiB windows sweeping forward, instead
// of 80K sparse streams. Staging via global_load_lds width=16 (no VGPR
// dest, fire-and-forget, 20 KiB outstanding/wave). Each wave stages the
// exact px range it computes -> no cross-wave LDS dependency; barriers
// only delimit stage/compute phases; 2 blocks/CU overlap each other.

#define CC 19
#define NBLK 512
#define NTHR 256
#define PXB 1024                      // px per block-tile (4 KiB per channel)
#define NITER 4                       // 512*1024*4 = 2,097,152 px exact
#define PXPB 262144                   // px per batch image (512*512)
#define IGNORE_IDX 255

typedef float f32x4 __attribute__((ext_vector_type(4)));
typedef int   i32x4 __attribute__((ext_vector_type(4)));

__device__ __forceinline__ void gload16(const void* g, void* l) {
    // global (per-lane addr) -> LDS (wave-uniform base + lane*16), async
    __builtin_amdgcn_global_load_lds(
        (const __attribute__((address_space(1))) unsigned int*)g,
        (__attribute__((address_space(3))) unsigned int*)l,
        16, 0, 0);
}

__global__ __launch_bounds__(NTHR, 2) void dice_accum(
    const float* __restrict__ logits,
    const int* __restrict__ targets,
    float* __restrict__ sums)         // sums[64]: 0-18 S, 19-37 I, 38-56 cnt
{
    __shared__ float s_log[CC * 1024];        // 19 channels x 1024 px (76 KiB)
    __shared__ int   s_tgt[1024];             // 4 KiB   -> total 80 KiB exact

    const int wv   = threadIdx.x >> 6;        // wave 0..3
    const int tx4  = threadIdx.x * 4;         // float/int offset of this lane's 16B

    float accS[CC], accI[CC], accC[CC];
#pragma unroll
    for (int c = 0; c < CC; ++c) { accS[c] = 0.f; accI[c] = 0.f; accC[c] = 0.f; }

#pragma unroll 1
    for (int it = 0; it < NITER; ++it) {
        // ---- dense tile mapping: concurrent blocks own CONSECUTIVE tiles ----
        const int tile  = it * NBLK + blockIdx.x;
        const int pxb   = tile * PXB;                 // global pixel base
        const int batch = pxb >> 18;                  // / PXPB
        const int hw    = pxb & (PXPB - 1);
        const float* pbase = logits + (((size_t)(batch * CC)) << 18) + hw;

        // ---- stage: 19 channels + targets, async into LDS ----
#pragma unroll
        for (int c = 0; c < CC; ++c)
            gload16(pbase + (((size_t)c) << 18) + tx4,
                    s_log + c * 1024 + wv * 256);
        gload16(targets + pxb + tx4, s_tgt + wv * 256);

        __syncthreads();                              // drains vmcnt -> LDS ready

        // ---- compute: 4 px/thread, channel order 0..18 (FP order preserved) --
        const i32x4 tt = ((const i32x4*)s_tgt)[threadIdx.x];

        f32x4 x[CC];
        float s0 = 0.f, s1 = 0.f, s2 = 0.f, s3 = 0.f;
#pragma unroll
        for (int c = 0; c < CC; ++c) {
            f32x4 v = ((const f32x4*)s_log)[c * 256 + threadIdx.x];
            v.x = __expf(v.x); s0 += v.x;
            v.y = __expf(v.y); s1 += v.y;
            v.z = __expf(v.z); s2 += v.z;
            v.w = __expf(v.w); s3 += v.w;
            x[c] = v;
        }
        const float i0 = (tt.x != IGNORE_IDX) ? __builtin_amdgcn_rcpf(s0) : 0.f;
        const float i1 = (tt.y != IGNORE_IDX) ? __builtin_amdgcn_rcpf(s1) : 0.f;
        const float i2 = (tt.z != IGNORE_IDX) ? __builtin_amdgcn_rcpf(s2) : 0.f;
        const float i3 = (tt.w != IGNORE_IDX) ? __builtin_amdgcn_rcpf(s3) : 0.f;

#pragma unroll
        for (int c = 0; c < CC; ++c) {
            accS[c] = fmaf(x[c].x, i0,
                      fmaf(x[c].y, i1,
                      fmaf(x[c].z, i2,
                      fmaf(x[c].w, i3, accS[c]))));
            const bool h0 = (tt.x == c), h1 = (tt.y == c);
            const bool h2 = (tt.z == c), h3 = (tt.w == c);
            accI[c] = fmaf(h0 ? x[c].x : 0.f, i0,
                      fmaf(h1 ? x[c].y : 0.f, i1,
                      fmaf(h2 ? x[c].z : 0.f, i2,
                      fmaf(h3 ? x[c].w : 0.f, i3, accI[c]))));
            accC[c] += (h0 ? 1.f : 0.f) + (h1 ? 1.f : 0.f)
                     + (h2 ? 1.f : 0.f) + (h3 ? 1.f : 0.f);
        }

        __syncthreads();                              // protect LDS before re-stage
    }

    // ---- wave-level reduce of the 57 accumulators ----
#pragma unroll
    for (int c = 0; c < CC; ++c) {
        for (int off = 32; off; off >>= 1) {
            accS[c] += __shfl_down(accS[c], off);
            accI[c] += __shfl_down(accI[c], off);
            accC[c] += __shfl_down(accC[c], off);
        }
    }

    // reuse staging LDS as reduction scratch (all compute done)
    float* s_part = s_log;                            // [4][64]
    const int lane = threadIdx.x & 63;
    if (lane == 0) {
#pragma unroll
        for (int c = 0; c < CC; ++c) {
            s_part[wv * 64 + c]          = accS[c];
            s_part[wv * 64 + CC + c]     = accI[c];
            s_part[wv * 64 + 2 * CC + c] = accC[c];
        }
    }
    __syncthreads();
    if (threadIdx.x < 3 * CC) {                       // 57 device-scope adds/block
        const float v = s_part[0 * 64 + threadIdx.x] + s_part[1 * 64 + threadIdx.x]
                      + s_part[2 * 64 + threadIdx.x] + s_part[3 * 64 + threadIdx.x];
        atomicAdd(&sums[threadIdx.x], v);
    }
}

__global__ __launch_bounds__(64) void dice_final(
    const float* __restrict__ sums, float* __restrict__ out)
{
    const int c = threadIdx.x;                        // one wave
    float term = 0.f, tv = 0.f;
    if (c < CC) {
        const float S = sums[c];
        const float I = sums[CC + c];
        const float N = sums[2 * CC + c];
        tv = N;
        term = 1.f - (2.f * I + 1.f) / (S + N + 1.f);
    }
#pragma unroll
    for (int off = 32; off; off >>= 1) {
        term += __shfl_down(term, off);
        tv   += __shfl_down(tv, off);
    }
    if (c == 0)
        out[0] = (tv > 0.f) ? term * (1.f / (float)CC) : 0.f;
}

extern "C" void kernel_launch(void* const* d_in, const int* in_sizes, int n_in,
                              void* d_out, int out_size, void* d_ws, size_t ws_size,
                              hipStream_t stream) {
    const float* logits = (const float*)d_in[0];
    const int* targets = (const int*)d_in[1];
    float* sums = (float*)d_ws;                       // 64 floats used
    float* out = (float*)d_out;

    hipMemsetAsync(sums, 0, 64 * sizeof(float), stream);   // ws is poisoned
    dice_accum<<<NBLK, NTHR, 0, stream>>>(logits, targets, sums);
    dice_final<<<1, 64, 0, stream>>>(sums, out);
}